// Round 5
// baseline (876.041 us; speedup 1.0000x reference)
//
#include <hip/hip_runtime.h>

#define N_NODES 500000
#define N_EDGES 8000000
#define FEAT 10
#define HID 32
#define N_TOOLS 13
#define N_PRIM 8

// ---- bucketing geometry ----------------------------------------------------
#define BK_BITS 8
#define BK_SIZE (1 << BK_BITS)                        // 256 nodes / bucket
#define NB ((N_NODES + BK_SIZE - 1) / BK_SIZE)        // 1954 buckets
#define SC_THREADS 512
#define SC_EPT 32
#define SC_CHUNK (SC_THREADS * SC_EPT)                // 16384 edges / block
#define SC_BLOCKS ((N_EDGES + SC_CHUNK - 1) / SC_CHUNK)  // 489
#define R_CH 8
#define ROWS_PER_CH ((SC_BLOCKS + R_CH - 1) / R_CH)   // 62
#define N_OCT 8                                       // src >> 16 in [0,8)

// ===========================================================================
// 1) per-block bucket histogram (LDS only, no global atomics)
// ===========================================================================
__global__ __launch_bounds__(SC_THREADS) void bhist_kernel(
    const int* __restrict__ dst, int* __restrict__ bhist) {
    __shared__ int hist[NB];  // 7.8 KB
    const int t = threadIdx.x;
    for (int i = t; i < NB; i += SC_THREADS) hist[i] = 0;
    __syncthreads();
    const int base = blockIdx.x * SC_CHUNK;
    for (int k = 0; k < SC_EPT; ++k) {
        int e = base + k * SC_THREADS + t;  // coalesced
        if (e < N_EDGES) atomicAdd(&hist[dst[e] >> BK_BITS], 1);
    }
    __syncthreads();
    int* row = bhist + (size_t)blockIdx.x * NB;
    for (int i = t; i < NB; i += SC_THREADS) row[i] = hist[i];
}

// ===========================================================================
// 2a) column partial sums over row chunks: ctmp[rc][c]
// ===========================================================================
__global__ __launch_bounds__(256) void scan_a_kernel(
    const int* __restrict__ bhist, int* __restrict__ ctmp) {
    const int rc = blockIdx.x >> 3;
    const int cc = blockIdx.x & 7;
    const int c = cc * 256 + threadIdx.x;
    if (c >= NB) return;
    const int r0 = rc * ROWS_PER_CH;
    const int r1 = (r0 + ROWS_PER_CH < SC_BLOCKS) ? r0 + ROWS_PER_CH : SC_BLOCKS;
    int s = 0;
    for (int r = r0; r < r1; ++r) s += bhist[(size_t)r * NB + c];  // coalesced
    ctmp[rc * NB + c] = s;
}

// ===========================================================================
// 2b) bucket starts (exclusive scan of column totals) + per-chunk starts
// ===========================================================================
__global__ __launch_bounds__(256) void scan_b_kernel(
    const int* __restrict__ ctmp, int* __restrict__ bstart,
    int* __restrict__ cstart) {
    __shared__ int colt[NB];  // 7.8 KB
    const int t = threadIdx.x;
    for (int c = t; c < NB; c += 256) {
        int s = 0;
#pragma unroll
        for (int rc = 0; rc < R_CH; ++rc) s += ctmp[rc * NB + c];
        colt[c] = s;
    }
    __syncthreads();
    if (t == 0) {
        int run = 0;
        for (int c = 0; c < NB; ++c) {
            int v = colt[c];
            colt[c] = run;
            run += v;
        }
        bstart[NB] = run;  // == N_EDGES
    }
    __syncthreads();
    for (int c = t; c < NB; c += 256) {
        int run = colt[c];
        bstart[c] = run;
#pragma unroll
        for (int rc = 0; rc < R_CH; ++rc) {
            cstart[rc * NB + c] = run;
            run += ctmp[rc * NB + c];
        }
    }
}

// ===========================================================================
// 2c) per-(block,bucket) exact offsets, in place in bhist
// ===========================================================================
__global__ __launch_bounds__(256) void scan_c_kernel(
    int* __restrict__ bhist, const int* __restrict__ cstart) {
    const int rc = blockIdx.x >> 3;
    const int cc = blockIdx.x & 7;
    const int c = cc * 256 + threadIdx.x;
    if (c >= NB) return;
    const int r0 = rc * ROWS_PER_CH;
    const int r1 = (r0 + ROWS_PER_CH < SC_BLOCKS) ? r0 + ROWS_PER_CH : SC_BLOCKS;
    int run = cstart[rc * NB + c];
    for (int r = r0; r < r1; ++r) {
        size_t i = (size_t)r * NB + c;
        int v = bhist[i];
        bhist[i] = run;
        run += v;
    }
}

// ===========================================================================
// 3) multisplit scatter: immediate write using precomputed bases.
//    basel comes from the scan (not local counting), so load it FIRST and
//    stream edges with no per-thread arrays -> EPT=32, longer runs.
// ===========================================================================
__global__ __launch_bounds__(SC_THREADS) void mscatter_kernel(
    const int* __restrict__ src, const int* __restrict__ dst,
    const int* __restrict__ bhist, int* __restrict__ store) {
    __shared__ int hist[NB];   // local rank counters
    __shared__ int basel[NB];  // global base offsets for this block
    const int t = threadIdx.x;
    const int* row = bhist + (size_t)blockIdx.x * NB;
    for (int i = t; i < NB; i += SC_THREADS) {
        hist[i] = 0;
        basel[i] = row[i];
    }
    __syncthreads();
    const int base = blockIdx.x * SC_CHUNK;
    for (int k = 0; k < SC_EPT; ++k) {
        int e = base + k * SC_THREADS + t;
        if (e < N_EDGES) {
            int d = dst[e];
            int s = src[e];
            int bkt = d >> BK_BITS;
            int pkd = ((d & (BK_SIZE - 1)) << 19) | s;  // src < 2^19
            int r = atomicAdd(&hist[bkt], 1);           // LDS atomic rank
            store[basel[bkt] + r] = pkd;
        }
    }
}

// ===========================================================================
// 4) fused: per-bucket LDS aggregation (8 src-octant passes for L2 locality)
//    + node transform + graph-embed partial reduction
// ===========================================================================
__global__ __launch_bounds__(256) void baggr_fused_kernel(
    const int* __restrict__ bstart, const int* __restrict__ store,
    const float* __restrict__ x,
    const float* __restrict__ w_self, const float* __restrict__ b_self,
    const float* __restrict__ w_neigh, const float* __restrict__ b_neigh,
    float* __restrict__ h_out, float* __restrict__ hsum) {
    __shared__ float lagg[BK_SIZE * FEAT];  // 10 KB
    __shared__ float lcnt[BK_SIZE];         // 1 KB
    __shared__ float red[4][HID];
    const int t = threadIdx.x;
    const int b = blockIdx.x;
    const int j = t & 31;  // invariant under +256 strides
    float ws[FEAT], wn[FEAT];
#pragma unroll
    for (int k = 0; k < FEAT; ++k) {
        ws[k] = w_self[k * HID + j];
        wn[k] = w_neigh[k * HID + j];
    }
    const float bias = b_self[j] + b_neigh[j];

    for (int i = t; i < BK_SIZE * FEAT; i += 256) lagg[i] = 0.0f;
    lcnt[t] = 0.0f;  // blockDim == BK_SIZE == 256
    __syncthreads();

    const int s0 = bstart[b], e0 = bstart[b + 1];
    // 8 passes over the (L1-resident, ~16 KB) segment; pass o gathers only
    // from x octant o (2.5 MB) so concurrent blocks keep it L2-resident.
    for (int oct = 0; oct < N_OCT; ++oct) {
        for (int o = s0 + t; o < e0; o += 256) {
            int v = store[o];       // coalesced; L1/L2 hit after pass 0
            int s = v & 0x7FFFF;
            if ((s >> 16) == oct) {
                int loc = v >> 19;  // 0..255
                const float2* xr = (const float2*)(x + (size_t)s * FEAT);
                float2 p0 = xr[0], p1 = xr[1], p2 = xr[2], p3 = xr[3],
                       p4 = xr[4];
                float* la = lagg + loc * FEAT;
                atomicAdd(&la[0], p0.x); atomicAdd(&la[1], p0.y);
                atomicAdd(&la[2], p1.x); atomicAdd(&la[3], p1.y);
                atomicAdd(&la[4], p2.x); atomicAdd(&la[5], p2.y);
                atomicAdd(&la[6], p3.x); atomicAdd(&la[7], p3.y);
                atomicAdd(&la[8], p4.x); atomicAdd(&la[9], p4.y);
                atomicAdd(&lcnt[loc], 1.0f);
            }
        }
    }
    __syncthreads();

    const int node0 = b << BK_BITS;
    const int lim = (N_NODES - node0 < BK_SIZE) ? (N_NODES - node0) : BK_SIZE;
    float partial = 0.0f;
#pragma unroll 4
    for (int k = 0; k < 32; ++k) {
        int idx = (k << 8) + t;  // 0..8191 over (node_local, j)
        int nl = idx >> 5;
        if (nl < lim) {
            float inv = 1.0f / fmaxf(lcnt[nl], 1.0f);
            const float* xr = x + (size_t)(node0 + nl) * FEAT;
            const float* la = lagg + nl * FEAT;
            float acc = bias;
#pragma unroll
            for (int kk = 0; kk < FEAT; ++kk)
                acc += xr[kk] * ws[kk] + la[kk] * inv * wn[kk];
            acc = fmaxf(acc, 0.0f);
            h_out[(size_t)node0 * HID + idx] = acc;  // coalesced
            partial += acc;
        }
    }

    partial += __shfl_down(partial, 32);
    const int wave = t >> 6, lane = t & 63;
    if (lane < 32) red[wave][lane] = partial;
    __syncthreads();
    if (t < 32) {
        float s2 = red[0][t] + red[1][t] + red[2][t] + red[3][t];
        atomicAdd(&hsum[t], s2);
    }
}

// ===========================================================================
// 5) heads
// ===========================================================================
__global__ void head_kernel(const float* __restrict__ hsum,
                            const float* __restrict__ w_act,
                            const float* __restrict__ b_act,
                            const float* __restrict__ w_prim,
                            const float* __restrict__ b_prim,
                            float* __restrict__ out) {
    __shared__ float ge[HID];
    const int t = threadIdx.x;
    if (t < HID) {
        const float g = hsum[t] * (1.0f / (float)N_NODES);
        ge[t] = g;
        out[N_TOOLS + N_PRIM + t] = g;
    }
    __syncthreads();
    if (t < N_TOOLS) {
        float a = b_act[t];
#pragma unroll
        for (int jj = 0; jj < HID; ++jj) a += ge[jj] * w_act[jj * N_TOOLS + t];
        out[t] = a;
    }
    if (t >= 32 && t < 32 + N_PRIM) {
        const int p = t - 32;
        float a = b_prim[p];
#pragma unroll
        for (int jj = 0; jj < HID; ++jj) a += ge[jj] * w_prim[jj * N_PRIM + p];
        out[N_TOOLS + p] = a;
    }
}

// ===========================================================================
// fallback path (round-1), used only if ws_size is tiny
// ===========================================================================
__global__ void scatter_kernel(const int* __restrict__ src,
                               const int* __restrict__ dst,
                               const float* __restrict__ x,
                               float* __restrict__ agg,
                               float* __restrict__ cnt) {
    int e = blockIdx.x * blockDim.x + threadIdx.x;
    if (e >= N_EDGES) return;
    int s = src[e];
    int d = dst[e];
    const float* xr = x + (size_t)s * FEAT;
    float* ar = agg + (size_t)d * FEAT;
#pragma unroll
    for (int k = 0; k < FEAT; ++k) atomicAdd(&ar[k], xr[k]);
    atomicAdd(&cnt[d], 1.0f);
}

__global__ void node_kernel(const float* __restrict__ x,
                            const float* __restrict__ agg,
                            const float* __restrict__ cnt,
                            const float* __restrict__ w_self,
                            const float* __restrict__ b_self,
                            const float* __restrict__ w_neigh,
                            const float* __restrict__ b_neigh,
                            float* __restrict__ h_out,
                            float* __restrict__ hsum) {
    const int j = threadIdx.x & 31;
    float ws[FEAT], wn[FEAT];
#pragma unroll
    for (int k = 0; k < FEAT; ++k) {
        ws[k] = w_self[k * HID + j];
        wn[k] = w_neigh[k * HID + j];
    }
    const float bias = b_self[j] + b_neigh[j];
    const long total = (long)N_NODES * HID;
    const long stride = (long)gridDim.x * blockDim.x;
    float partial = 0.0f;
    for (long idx = (long)blockIdx.x * blockDim.x + threadIdx.x; idx < total;
         idx += stride) {
        const int i = (int)(idx >> 5);
        const float inv = 1.0f / fmaxf(cnt[i], 1.0f);
        const float* xr = x + (size_t)i * FEAT;
        const float* ar = agg + (size_t)i * FEAT;
        float acc = bias;
#pragma unroll
        for (int k = 0; k < FEAT; ++k) {
            acc += xr[k] * ws[k];
            acc += (ar[k] * inv) * wn[k];
        }
        acc = fmaxf(acc, 0.0f);
        h_out[idx] = acc;
        partial += acc;
    }
    partial += __shfl_down(partial, 32);
    __shared__ float red[4][HID];
    const int wave = threadIdx.x >> 6;
    const int lane = threadIdx.x & 63;
    if (lane < 32) red[wave][lane] = partial;
    __syncthreads();
    if (threadIdx.x < 32) {
        float s = red[0][threadIdx.x] + red[1][threadIdx.x] +
                  red[2][threadIdx.x] + red[3][threadIdx.x];
        atomicAdd(&hsum[threadIdx.x], s);
    }
}

extern "C" void kernel_launch(void* const* d_in, const int* in_sizes, int n_in,
                              void* d_out, int out_size, void* d_ws,
                              size_t ws_size, hipStream_t stream) {
    const float* x       = (const float*)d_in[0];
    const int*   ei      = (const int*)d_in[1];
    const float* w_self  = (const float*)d_in[2];
    const float* b_self  = (const float*)d_in[3];
    const float* w_neigh = (const float*)d_in[4];
    const float* b_neigh = (const float*)d_in[5];
    const float* w_act   = (const float*)d_in[6];
    const float* b_act   = (const float*)d_in[7];
    const float* w_prim  = (const float*)d_in[8];
    const float* b_prim  = (const float*)d_in[9];
    float* out = (float*)d_out;
    const int* src = ei;
    const int* dst = ei + N_EDGES;

    // ws layout (4B elems):
    //   bhist [SC_BLOCKS*NB] | ctmp [R_CH*NB] | cstart [R_CH*NB]
    //   | bstart [NB+1] | store [E] | hsum [HID]          (~36 MB)
    const size_t n_bhist = (size_t)SC_BLOCKS * NB;
    const size_t n_ctmp  = (size_t)R_CH * NB;
    const size_t n_bst   = NB + 1;
    const size_t need =
        (n_bhist + 2 * n_ctmp + n_bst + (size_t)N_EDGES + HID) * 4;

    if (ws_size >= need) {
        int*   bhist  = (int*)d_ws;
        int*   ctmp   = bhist + n_bhist;
        int*   cstart = ctmp + n_ctmp;
        int*   bstart = cstart + n_ctmp;
        int*   store  = bstart + n_bst;
        float* hsum   = (float*)(store + N_EDGES);

        hipMemsetAsync(hsum, 0, HID * sizeof(float), stream);

        bhist_kernel<<<SC_BLOCKS, SC_THREADS, 0, stream>>>(dst, bhist);
        scan_a_kernel<<<64, 256, 0, stream>>>(bhist, ctmp);
        scan_b_kernel<<<1, 256, 0, stream>>>(ctmp, bstart, cstart);
        scan_c_kernel<<<64, 256, 0, stream>>>(bhist, cstart);
        mscatter_kernel<<<SC_BLOCKS, SC_THREADS, 0, stream>>>(src, dst, bhist,
                                                              store);
        baggr_fused_kernel<<<NB, 256, 0, stream>>>(
            bstart, store, x, w_self, b_self, w_neigh, b_neigh,
            out + (N_TOOLS + N_PRIM + HID), hsum);
        head_kernel<<<1, 64, 0, stream>>>(hsum, w_act, b_act, w_prim, b_prim,
                                          out);
    } else {
        float* agg  = (float*)d_ws;
        float* cnt  = agg + (size_t)N_NODES * FEAT;
        float* hsum = cnt + N_NODES;
        const size_t zero_bytes =
            ((size_t)N_NODES * FEAT + N_NODES + HID) * sizeof(float);
        hipMemsetAsync(d_ws, 0, zero_bytes, stream);

        scatter_kernel<<<(N_EDGES + 255) / 256, 256, 0, stream>>>(src, dst, x,
                                                                  agg, cnt);
        node_kernel<<<4096, 256, 0, stream>>>(
            x, agg, cnt, w_self, b_self, w_neigh, b_neigh,
            out + (N_TOOLS + N_PRIM + HID), hsum);
        head_kernel<<<1, 64, 0, stream>>>(hsum, w_act, b_act, w_prim, b_prim,
                                          out);
    }
}